// Round 26
// baseline (241.840 us; speedup 1.0000x reference)
//
#include <hip/hip_runtime.h>
#include <hip/hip_bf16.h>

#define B_ 8
#define S_ 2048
#define DM 1024
#define H_ 16
#define DH 64
#define DK 384

#define AS3 __attribute__((address_space(3)))
#define AS1 __attribute__((address_space(1)))
typedef unsigned int u32;

typedef __attribute__((ext_vector_type(8))) short bf16x8;
typedef __attribute__((ext_vector_type(4))) short bf16x4;
typedef __attribute__((ext_vector_type(4))) float f32x4;

static __device__ __forceinline__ ushort f2b(float f) {
  __hip_bfloat16 h = __float2bfloat16(f);
  return *reinterpret_cast<ushort*>(&h);
}
static __device__ __forceinline__ float b2f(ushort u) {
  __hip_bfloat16 h;
  *reinterpret_cast<ushort*>(&h) = u;
  return __bfloat162float(h);
}

// ---------------- K0: convert X and Wk/Wv/Wb to bf16 (once) --------------------
__global__ __launch_bounds__(256) void k_cvt(
    const float* __restrict__ X, const float* __restrict__ Wk,
    const float* __restrict__ Wv, const float* __restrict__ Wb,
    ushort* __restrict__ Xb, ushort* __restrict__ Wball) {
  const int total = 2097152 + 3 * 131072;
  int c = blockIdx.x * 256 + threadIdx.x;
  const int stride = gridDim.x * 256;
  for (; c < total; c += stride) {
    const float* s;
    ushort* d;
    size_t off;
    if (c < 2097152) { s = X; d = Xb; off = (size_t)c; }
    else {
      int cc = c - 2097152;
      int wsel = cc >> 17;
      off = (size_t)(cc & 131071);
      s = wsel == 0 ? Wk : (wsel == 1 ? Wv : Wb);
      d = Wball + (size_t)wsel * (DM * DM);
    }
    float4 a = *(const float4*)(s + off * 8);
    float4 b = *(const float4*)(s + off * 8 + 4);
    ushort u[8] = { f2b(a.x), f2b(a.y), f2b(a.z), f2b(a.w),
                    f2b(b.x), f2b(b.y), f2b(b.z), f2b(b.w) };
    *(uint4*)(d + off * 8) = *(uint4*)u;
  }
}

// ---------------- K1: projection GEMM  Y = Xb @ Wb^T ---------------------------
// BM=256 x BN=256, BK=32 (arith intensity 128 MACs/byte, 1.5x round-25), 512
// threads (8 waves of 128x64), 3-buffer counted-vmcnt pipeline (depth-2,
// vmcnt(4), one raw barrier/K-step), round-19 verified chunk permutation
//   q(row,kslot) = row*4 + (kslot ^ ((row>>1)&3))   per 16-row chunk
// (coalesced staging AND conflict-free b128 reads). Two-half epilogue bounce.
__global__ __launch_bounds__(512) void k_proj(
    const ushort* __restrict__ Xb, const ushort* __restrict__ Wball,
    ushort* __restrict__ kvb) {
  __shared__ ushort SH[3 * 16384];             // 3 bufs x (A 16KB | B 16KB) = 96KB
  const int t = threadIdx.x, lane = t & 63, w = t >> 6;
  const int wm = w >> 2, wn = w & 3;           // 2 x 4 waves of 128x64
  const int l15 = lane & 15, lq = lane >> 4;
  // Grid (64, 4, 3). XCD c = bid&7; within XCD: z slowest, m-group, n fastest.
  const int bid = blockIdx.x + (blockIdx.y << 6) + (blockIdx.z << 8);
  const int c = bid & 7, r = bid >> 3;         // r in 0..95
  const int zb = r >> 5;                       // wsel 0..2
  const int rem = r & 31;
  const int mgrp = rem >> 2;                   // 0..7
  const int nb = rem & 3;                      // 0..3
  const int m0 = (c * 8 + mgrp) * 256;
  const int n0 = nb * 256;
  const int wsel = zb;
  const ushort* Wmat = Wball + (size_t)wsel * (DM * DM);
  ushort* out = kvb + (size_t)wsel * ((size_t)B_ * H_ * S_ * DH);

  // Staging: call covers 128 rows (8 chunks of 16 rows x 4 slots). Thread t:
  // chunk t>>6, within-chunk lane q=t&63 -> row q>>2, permuted k-slot.
  const int chk = t >> 6;                      // 0..7
  const int ql = t & 63;
  const int srow = ql >> 2;                    // 0..15
  const int scol8 = ((ql & 3) ^ ((ql >> 3) & 3)) * 8;

  const ushort* pA[2];
  const ushort* pB[2];
  #pragma unroll
  for (int j = 0; j < 2; j++) {
    pA[j] = Xb + (size_t)(m0 + j * 128 + chk * 16 + srow) * DM + scol8;
    pB[j] = Wmat + (size_t)(n0 + j * 128 + chk * 16 + srow) * DM + scol8;
  }

  auto STAGE = [&](int buf, int kidx) {        // 4 calls, 8KB each
    ushort* base = SH + buf * 16384;
    #pragma unroll
    for (int j = 0; j < 2; j++)
      __builtin_amdgcn_global_load_lds(
          (const AS1 u32*)(pA[j] + kidx * 32),
          (AS3 u32*)(base + j * 4096 + t * 8), 16, 0, 0);
    #pragma unroll
    for (int j = 0; j < 2; j++)
      __builtin_amdgcn_global_load_lds(
          (const AS1 u32*)(pB[j] + kidx * 32),
          (AS3 u32*)(base + 8192 + j * 4096 + t * 8), 16, 0, 0);
  };

  // Fragment read: (chunk g, row l15, kslot lq) -> g*512 + q(l15,lq)*8
  const int rofs = (l15 * 4 + (lq ^ ((l15 >> 1) & 3))) * 8;

  f32x4 acc[8][4] = {};
  STAGE(0, 0);
  STAGE(1, 1);                                 // 8 calls in flight
  #pragma unroll
  for (int kt = 0; kt < 32; kt++) {
    if (kt < 31) asm volatile("s_waitcnt vmcnt(4)" ::: "memory");  // tile-kt landed
    else         asm volatile("s_waitcnt vmcnt(0)" ::: "memory");
    __builtin_amdgcn_s_barrier();              // tile-kt ready; buf kt-1 reads done
    if (kt < 30) STAGE((kt + 2) % 3, kt + 2);  // overwrites buf(kt-1): safe
    const ushort* Ab = SH + (kt % 3) * 16384;
    __builtin_amdgcn_s_setprio(1);
    bf16x8 af[8], bfr[4];
    #pragma unroll
    for (int mi = 0; mi < 8; mi++)
      af[mi] = *(const bf16x8*)&Ab[(wm * 8 + mi) * 512 + rofs];
    #pragma unroll
    for (int ni = 0; ni < 4; ni++)
      bfr[ni] = *(const bf16x8*)&Ab[8192 + (wn * 4 + ni) * 512 + rofs];
    #pragma unroll
    for (int mi = 0; mi < 8; mi++)
      #pragma unroll
      for (int ni = 0; ni < 4; ni++)
        acc[mi][ni] = __builtin_amdgcn_mfma_f32_16x16x32_bf16(af[mi], bfr[ni], acc[mi][ni], 0, 0, 0);
    __builtin_amdgcn_s_setprio(0);
  }
  __syncthreads();                             // all reads done before Cb aliasing

  // Epilogue: two 128-row half bounces (Cb 128x264 = 67.6KB, aliases SH).
  ushort (*Cb)[264] = (ushort (*)[264])SH;
  #pragma unroll
  for (int hf = 0; hf < 2; hf++) {
    if (wm == hf) {
      #pragma unroll
      for (int mi = 0; mi < 8; mi++)
        #pragma unroll
        for (int ni = 0; ni < 4; ni++)
          #pragma unroll
          for (int rr = 0; rr < 4; rr++) {
            float val = acc[mi][ni][rr];
            if (wsel == 2) val = 1.0f / (1.0f + __expf(-val));
            Cb[mi * 16 + lq * 4 + rr][wn * 64 + ni * 16 + l15] = f2b(val);
          }
    }
    __syncthreads();
    #pragma unroll
    for (int q = 0; q < 8; q++) {
      int idx = q * 512 + t;                   // 4096 = 128 rows x 32 slots
      int lm = idx >> 5;
      int c16 = idx & 31;
      int m = m0 + hf * 128 + lm;
      int b = m >> 11, s = m & 2047;
      int o0 = n0 + c16 * 8;
      int h = o0 >> 6, d = o0 & 63;
      *(uint4*)(out + (((size_t)(b * H_ + h)) * S_ + s) * DH + d) =
          *(uint4*)&Cb[lm][c16 * 8];
    }
    __syncthreads();
  }
}

// ---------------- K2: fused DPFP + num + gate + assoc (register streaming) -----
__global__ __launch_bounds__(512) void k_fused6(
    const ushort* __restrict__ Kb, const ushort* __restrict__ Vb,
    const ushort* __restrict__ Bgb, const float* __restrict__ Wmem,
    const float* __restrict__ z, ushort* __restrict__ part) {
  __shared__ u32 mkLd[32][192];     // raw mk, perm-k pairs, XOR-swizzled (24 KB)
  __shared__ ushort mkT[384][36];   // raw mk, [true feat][s] (27.6 KB)
  __shared__ ushort gLT[64][36];    // inv-folded gated, [d][s] (4.6 KB)
  __shared__ ushort zL[384];        // permuted z (bf16)
  const int t = threadIdx.x, l = t & 63, w = t >> 6;
  const int l15 = l & 15, lq = l >> 4;
  const int bh = blockIdx.y, seg = blockIdx.x;
  const size_t rowbase = (size_t)bh * S_;
  const int mi = w >> 2, ni = w & 3;
  const int dcol = ni * 16 + l15;

  for (int cc = t; cc < DK; cc += 512) {
    int u = cc >> 7, p = (cc & 127) >> 1, par = cc & 1;
    zL[cc] = f2b(z[(size_t)bh * DK + u * 128 + par * 64 + p]);
  }

  const float* Wm = Wmem + (size_t)bh * (DK * DH);
  bf16x8 bw[12];
  #pragma unroll
  for (int k0i = 0; k0i < 12; k0i++) {
    bf16x8 tmp;
    #pragma unroll
    for (int j = 0; j < 8; j++) {
      int cc = k0i * 32 + lq * 8 + j;
      int u = cc >> 7, p = (cc & 127) >> 1, par = cc & 1;
      tmp[j] = (short)f2b(Wm[(size_t)(u * 128 + par * 64 + p) * DH + dcol]);
    }
    bw[k0i] = tmp;
  }

  f32x4 acc[3][4] = {};
  ushort kreg[4], vreg[4], breg[4];

  auto LOADCH = [&](int ch) {
    const int s0 = seg * 512 + ch * 32;
    #pragma unroll
    for (int r = 0; r < 4; r++)
      kreg[r] = Kb[(rowbase + s0 + w * 4 + r) * DH + l];
    #pragma unroll
    for (int rr = 0; rr < 4; rr++) {
      size_t ga = (rowbase + s0 + mi * 16 + lq * 4 + rr) * DH + dcol;
      vreg[rr] = Vb[ga];
      breg[rr] = Bgb[ga];
    }
  };

  LOADCH(0);
  __syncthreads();   // zL ready

  for (int ch = 0; ch < 16; ch++) {
    float xpv[4], xnv[4];
    u32 pks[4];
    #pragma unroll
    for (int r = 0; r < 4; r++) {
      float kv = b2f(kreg[r]);
      xpv[r] = fmaxf(kv, 0.f);
      xnv[r] = fmaxf(-kv, 0.f);
      pks[r] = (u32)f2b(xpv[r]) | ((u32)f2b(xnv[r]) << 16);
    }
    ushort4 mp[6];
    #pragma unroll
    for (int u = 0; u < 3; u++) {
      int ie = (l - u - 1) & 127;
      int sl = ie & 63;
      bool sw = ie >= 64;
      #pragma unroll
      for (int r = 0; r < 4; r++) {
        u32 pp = (u32)__shfl((int)pks[r], sl);
        float ps = b2f((ushort)(pp & 0xffff));
        float ns = b2f((ushort)(pp >> 16));
        float xbe = sw ? ns : ps;
        float xbo = sw ? ps : ns;
        ushort bve = f2b(xpv[r] * xbe);
        ushort bvo = f2b(xnv[r] * xbo);
        int row = w * 4 + r;
        mkLd[row][(u * 64 + l) ^ ((row & 7) << 2)] = (u32)bve | ((u32)bvo << 16);
        ((ushort*)&mp[2 * u])[r] = bve;
        ((ushort*)&mp[2 * u + 1])[r] = bvo;
      }
    }
    #pragma unroll
    for (int tt = 0; tt < 6; tt++)
      *(ushort4*)&mkT[l + 64 * tt][w * 4] = mp[tt];
    __syncthreads();   // A: mkLd/mkT ready

    const u32* mkrow = &mkLd[mi * 16 + l15][0];
    const int xr = (l15 & 7) << 2;
    f32x4 an0 = {}, an1 = {}, gacc = {}, zacc = {};
    __builtin_amdgcn_s_setprio(1);
    #pragma unroll
    for (int k0i = 0; k0i < 12; k0i += 2) {
      bf16x8 afA = *(const bf16x8*)(mkrow + ((k0i * 16 + lq * 4) ^ xr));
      bf16x8 afB = *(const bf16x8*)(mkrow + (((k0i + 1) * 16 + lq * 4) ^ xr));
      bf16x8 zfA = *(const bf16x8*)&zL[k0i * 32 + lq * 8];
      bf16x8 zfB = *(const bf16x8*)&zL[(k0i + 1) * 32 + lq * 8];
      an0 = __builtin_amdgcn_mfma_f32_16x16x32_bf16(afA, bw[k0i], an0, 0, 0, 0);
      an1 = __builtin_amdgcn_mfma_f32_16x16x32_bf16(afB, bw[k0i + 1], an1, 0, 0, 0);
      gacc = __builtin_amdgcn_mfma_f32_16x16x32_bf16(afA, afA, gacc, 0, 0, 0);
      gacc = __builtin_amdgcn_mfma_f32_16x16x32_bf16(afB, afB, gacc, 0, 0, 0);
      zacc = __builtin_amdgcn_mfma_f32_16x16x32_bf16(afA, zfA, zacc, 0, 0, 0);
      zacc = __builtin_amdgcn_mfma_f32_16x16x32_bf16(afB, zfB, zacc, 0, 0, 0);
    }
    __builtin_amdgcn_s_setprio(0);
    f32x4 an = an0 + an1;
    float ssqv[4];
    #pragma unroll
    for (int rr = 0; rr < 4; rr++)
      ssqv[rr] = __shfl(gacc[rr], (lq << 4) + lq * 4 + rr);
    {
      ushort4 gp;
      #pragma unroll
      for (int rr = 0; rr < 4; rr++) {
        float inv = 1.0f / fmaxf(sqrtf(ssqv[rr]), 1e-12f);
        float rden = 1.0f / (inv * zacc[rr] + 1e-5f);
        float prev = an[rr] * inv * rden;
        float g = (b2f(vreg[rr]) - prev) * b2f(breg[rr]);
        ((ushort*)&gp)[rr] = f2b(g * inv);
      }
      *(ushort4*)&gLT[dcol][mi * 16 + lq * 4] = gp;
    }
    __syncthreads();   // B: gLT ready

    if (ch < 15) LOADCH(ch + 1);   // prefetch next chunk under assoc

    {
      bf16x8 bfr[4];
      #pragma unroll
      for (int n2 = 0; n2 < 4; n2++) {
        bf16x4 blo = *(const bf16x4*)&gLT[n2 * 16 + l15][lq * 8];
        bf16x4 bhi = *(const bf16x4*)&gLT[n2 * 16 + l15][lq * 8 + 4];
        bfr[n2] = __builtin_shufflevector(blo, bhi, 0, 1, 2, 3, 4, 5, 6, 7);
      }
      __builtin_amdgcn_s_setprio(1);
      #pragma unroll
      for (int m2 = 0; m2 < 3; m2++) {
        bf16x4 alo = *(const bf16x4*)&mkT[w * 48 + m2 * 16 + l15][lq * 8];
        bf16x4 ahi = *(const bf16x4*)&mkT[w * 48 + m2 * 16 + l15][lq * 8 + 4];
        bf16x8 af = __builtin_shufflevector(alo, ahi, 0, 1, 2, 3, 4, 5, 6, 7);
        #pragma unroll
        for (int n2 = 0; n2 < 4; n2++)
          acc[m2][n2] = __builtin_amdgcn_mfma_f32_16x16x32_bf16(af, bfr[n2], acc[m2][n2], 0, 0, 0);
      }
      __builtin_amdgcn_s_setprio(0);
    }
    __syncthreads();   // C: assoc reads done before next phase-1 writes
  }

  ushort* pb = part + ((size_t)bh * 4 + seg) * (DK * DH);
  #pragma unroll
  for (int m2 = 0; m2 < 3; m2++)
    #pragma unroll
    for (int n2 = 0; n2 < 4; n2++)
      #pragma unroll
      for (int rc = 0; rc < 4; rc++)
        pb[(size_t)(w * 48 + m2 * 16 + lq * 4 + rc) * DH + n2 * 16 + l15] =
            f2b(acc[m2][n2][rc]);
}

// ---------------- K3: out = Wmem + sum of 4 bf16 partials ----------------------
__global__ __launch_bounds__(256) void k_reduce(
    const float* __restrict__ Wmem, const ushort* __restrict__ part,
    float* __restrict__ out) {
  size_t i4 = (size_t)blockIdx.x * 256 + threadIdx.x;
  int bh = (int)(i4 / 6144);
  size_t r4 = i4 - (size_t)bh * 6144;
  float4 acc = *(const float4*)(Wmem + i4 * 4);
  #pragma unroll
  for (int k = 0; k < 4; k++) {
    const ushort* pp = part + ((size_t)bh * 4 + k) * (DK * DH) + r4 * 4;
    ushort4 pv = *(const ushort4*)pp;
    acc.x += b2f(pv.x);
    acc.y += b2f(pv.y);
    acc.z += b2f(pv.z);
    acc.w += b2f(pv.w);
  }
  *(float4*)(out + i4 * 4) = acc;
}

extern "C" void kernel_launch(void* const* d_in, const int* in_sizes, int n_in,
                              void* d_out, int out_size, void* d_ws, size_t ws_size,
                              hipStream_t stream) {
  const float* X  = (const float*)d_in[0];
  const float* Wk = (const float*)d_in[1];
  const float* Wv = (const float*)d_in[2];
  const float* Wb = (const float*)d_in[3];
  const float* Wm = (const float*)d_in[4];
  const float* z  = (const float*)d_in[5];
  float* out = (float*)d_out;
  char* ws = (char*)d_ws;

  // ws layout (~140.5 MB; ws_size >= 170 MB proven):
  //   Xb    : 0          .. 33,554,432   (dead after k_proj; part aliases)
  //   Wball : 33,554,432 .. 39,845,888
  //   kvb   : 39,845,888 .. 140,509,184  (K | V | sig(B))
  ushort* Xb    = (ushort*)(ws);
  ushort* Wball = (ushort*)(ws + 33554432ull);
  ushort* kvb   = (ushort*)(ws + 39845888ull);
  ushort* part  = (ushort*)(ws);                  // 25.2 MB, aliases dead Xb
  ushort* Kb  = kvb;
  ushort* Vb  = kvb + (size_t)B_ * H_ * S_ * DH;
  ushort* Bgb = kvb + 2ull * (size_t)B_ * H_ * S_ * DH;

  k_cvt   <<<dim3(2048), 256, 0, stream>>>(X, Wk, Wv, Wb, Xb, Wball);
  k_proj  <<<dim3(64, 4, 3), 512, 0, stream>>>(Xb, Wball, kvb);
  k_fused6<<<dim3(4, B_ * H_), 512, 0, stream>>>(Kb, Vb, Bgb, Wm, z, part);
  k_reduce<<<dim3(3072), 256, 0, stream>>>(Wm, part, out);
}

// Round 27
// 239.363 us; speedup vs baseline: 1.0104x; 1.0104x over previous
//
#include <hip/hip_runtime.h>
#include <hip/hip_bf16.h>

#define B_ 8
#define S_ 2048
#define DM 1024
#define H_ 16
#define DH 64
#define DK 384

#define AS3 __attribute__((address_space(3)))
#define AS1 __attribute__((address_space(1)))
typedef unsigned int u32;

typedef __attribute__((ext_vector_type(8))) short bf16x8;
typedef __attribute__((ext_vector_type(4))) short bf16x4;
typedef __attribute__((ext_vector_type(4))) float f32x4;

static __device__ __forceinline__ ushort f2b(float f) {
  __hip_bfloat16 h = __float2bfloat16(f);
  return *reinterpret_cast<ushort*>(&h);
}
static __device__ __forceinline__ float b2f(ushort u) {
  __hip_bfloat16 h;
  *reinterpret_cast<ushort*>(&h) = u;
  return __bfloat162float(h);
}

// ---------------- K0: convert X and Wk/Wv/Wb to bf16 (once) --------------------
__global__ __launch_bounds__(256) void k_cvt(
    const float* __restrict__ X, const float* __restrict__ Wk,
    const float* __restrict__ Wv, const float* __restrict__ Wb,
    ushort* __restrict__ Xb, ushort* __restrict__ Wball) {
  const int total = 2097152 + 3 * 131072;
  int c = blockIdx.x * 256 + threadIdx.x;
  const int stride = gridDim.x * 256;
  for (; c < total; c += stride) {
    const float* s;
    ushort* d;
    size_t off;
    if (c < 2097152) { s = X; d = Xb; off = (size_t)c; }
    else {
      int cc = c - 2097152;
      int wsel = cc >> 17;
      off = (size_t)(cc & 131071);
      s = wsel == 0 ? Wk : (wsel == 1 ? Wv : Wb);
      d = Wball + (size_t)wsel * (DM * DM);
    }
    float4 a = *(const float4*)(s + off * 8);
    float4 b = *(const float4*)(s + off * 8 + 4);
    ushort u[8] = { f2b(a.x), f2b(a.y), f2b(a.z), f2b(a.w),
                    f2b(b.x), f2b(b.y), f2b(b.z), f2b(b.w) };
    *(uint4*)(d + off * 8) = *(uint4*)u;
  }
}

// ---------------- K1: projection GEMM  Y = Xb @ Wb^T ---------------------------
// Round-25 proven best: BM=256 x BN=128, BK=64, 512 threads, 3-buffer pipeline,
// counted vmcnt(6), one raw barrier per K-step, XOR swizzle, hoisted ptrs,
// z-slowest within-XCD ordering (FETCH 98 MB), T5 setprio on MFMAs.
__global__ __launch_bounds__(512) void k_proj(
    const ushort* __restrict__ Xb, const ushort* __restrict__ Wball,
    ushort* __restrict__ kvb) {
  __shared__ ushort SH[3 * 24576];             // 3 bufs x (A 32KB | B 16KB) = 144KB
  const int t = threadIdx.x, lane = t & 63, w = t >> 6;
  const int wm = w >> 1, wn = w & 1;           // 4 x 2 waves of 64x64
  const int l15 = lane & 15, lq = lane >> 4;
  // Grid (64, 8, 3). XCD c = bid&7; within XCD: z slowest, m-group, n fastest.
  const int bid = blockIdx.x + (blockIdx.y << 6) + (blockIdx.z << 9);
  const int c = bid & 7, r = bid >> 3;         // r in 0..191
  const int zb = r >> 6;                       // wsel 0..2
  const int rem = r & 63;
  const int mgrp = rem >> 3;                   // 0..7
  const int nb = rem & 7;                      // 0..7
  const int m0 = (c * 8 + mgrp) * 256;
  const int n0 = nb * 128;
  const int wsel = zb;
  const ushort* Wmat = Wball + (size_t)wsel * (DM * DM);
  ushort* out = kvb + (size_t)wsel * ((size_t)B_ * H_ * S_ * DH);

  // Staging: call j covers 64 rows; thread t -> row j*64+(t>>3), swizzled slot.
  const int srow = t >> 3;                     // 0..63
  const int scol8 = ((t & 7) ^ (srow & 7)) * 8;

  const ushort* pA[4];
  const ushort* pB[2];
  #pragma unroll
  for (int j = 0; j < 4; j++)
    pA[j] = Xb + (size_t)(m0 + j * 64 + srow) * DM + scol8;
  #pragma unroll
  for (int j = 0; j < 2; j++)
    pB[j] = Wmat + (size_t)(n0 + j * 64 + srow) * DM + scol8;

  auto STAGE = [&](int buf, int kidx) {        // 6 calls, 8KB each
    ushort* base = SH + buf * 24576;
    #pragma unroll
    for (int j = 0; j < 4; j++)
      __builtin_amdgcn_global_load_lds(
          (const AS1 u32*)(pA[j] + kidx * 64),
          (AS3 u32*)(base + j * 4096 + t * 8), 16, 0, 0);
    #pragma unroll
    for (int j = 0; j < 2; j++)
      __builtin_amdgcn_global_load_lds(
          (const AS1 u32*)(pB[j] + kidx * 64),
          (AS3 u32*)(base + 16384 + j * 4096 + t * 8), 16, 0, 0);
  };

  // Fragment-read bases (row pitch 64 ushorts; read XOR uses l15&7 = lane&7).
  const int aoffb = (wm * 64 + l15) * 64;      // + mi*1024 + csw
  const int boffb = 16384 + (wn * 64 + l15) * 64;
  const int csw0 = (lq ^ (lane & 7)) << 3;
  const int csw1 = ((lq + 4) ^ (lane & 7)) << 3;

  f32x4 acc[4][4] = {};
  STAGE(0, 0);
  STAGE(1, 1);                                 // 12 calls in flight
  #pragma unroll
  for (int kt = 0; kt < 16; kt++) {
    if (kt < 15) asm volatile("s_waitcnt vmcnt(6)" ::: "memory");  // tile-kt landed
    else         asm volatile("s_waitcnt vmcnt(0)" ::: "memory");
    __builtin_amdgcn_s_barrier();              // all waves' tile-kt data ready;
                                               // all waves done reading buf kt-1
    if (kt < 14) STAGE((kt + 2) % 3, kt + 2);  // overwrites buf(kt-1): safe
    const ushort* Ab = SH + (kt % 3) * 24576;
    __builtin_amdgcn_s_setprio(1);
    #pragma unroll
    for (int kk2 = 0; kk2 < 2; kk2++) {
      const int csw = kk2 ? csw1 : csw0;
      bf16x8 af[4], bfr[4];
      #pragma unroll
      for (int mi = 0; mi < 4; mi++)
        af[mi] = *(const bf16x8*)&Ab[aoffb + mi * 1024 + csw];
      #pragma unroll
      for (int ni = 0; ni < 4; ni++)
        bfr[ni] = *(const bf16x8*)&Ab[boffb + ni * 1024 + csw];
      #pragma unroll
      for (int mi = 0; mi < 4; mi++)
        #pragma unroll
        for (int ni = 0; ni < 4; ni++)
          acc[mi][ni] = __builtin_amdgcn_mfma_f32_16x16x32_bf16(af[mi], bfr[ni], acc[mi][ni], 0, 0, 0);
    }
    __builtin_amdgcn_s_setprio(0);
  }
  __syncthreads();                             // all reads done before Cb aliasing

  // Epilogue: 256x136 LDS bounce (aliases SH), coalesced stores.
  ushort (*Cb)[136] = (ushort (*)[136])SH;
  #pragma unroll
  for (int mi = 0; mi < 4; mi++)
    #pragma unroll
    for (int ni = 0; ni < 4; ni++)
      #pragma unroll
      for (int rr = 0; rr < 4; rr++) {
        float val = acc[mi][ni][rr];
        if (wsel == 2) val = 1.0f / (1.0f + __expf(-val));
        Cb[wm * 64 + mi * 16 + lq * 4 + rr][wn * 64 + ni * 16 + l15] = f2b(val);
      }
  __syncthreads();
  #pragma unroll
  for (int q = 0; q < 8; q++) {
    int idx = q * 512 + t;                     // 4096 = 256 rows x 16 slots
    int lm = idx >> 4;
    int c16 = idx & 15;
    int m = m0 + lm;
    int b = m >> 11, s = m & 2047;
    int o0 = n0 + c16 * 8;
    int h = o0 >> 6, d = o0 & 63;
    *(uint4*)(out + (((size_t)(b * H_ + h)) * S_ + s) * DH + d) =
        *(uint4*)&Cb[lm][c16 * 8];
  }
}

// ---------------- K2: fused DPFP + num + gate + assoc (register streaming) -----
__global__ __launch_bounds__(512) void k_fused6(
    const ushort* __restrict__ Kb, const ushort* __restrict__ Vb,
    const ushort* __restrict__ Bgb, const float* __restrict__ Wmem,
    const float* __restrict__ z, ushort* __restrict__ part) {
  __shared__ u32 mkLd[32][192];     // raw mk, perm-k pairs, XOR-swizzled (24 KB)
  __shared__ ushort mkT[384][36];   // raw mk, [true feat][s] (27.6 KB)
  __shared__ ushort gLT[64][36];    // inv-folded gated, [d][s] (4.6 KB)
  __shared__ ushort zL[384];        // permuted z (bf16)
  const int t = threadIdx.x, l = t & 63, w = t >> 6;
  const int l15 = l & 15, lq = l >> 4;
  const int bh = blockIdx.y, seg = blockIdx.x;
  const size_t rowbase = (size_t)bh * S_;
  const int mi = w >> 2, ni = w & 3;
  const int dcol = ni * 16 + l15;

  for (int cc = t; cc < DK; cc += 512) {
    int u = cc >> 7, p = (cc & 127) >> 1, par = cc & 1;
    zL[cc] = f2b(z[(size_t)bh * DK + u * 128 + par * 64 + p]);
  }

  const float* Wm = Wmem + (size_t)bh * (DK * DH);
  bf16x8 bw[12];
  #pragma unroll
  for (int k0i = 0; k0i < 12; k0i++) {
    bf16x8 tmp;
    #pragma unroll
    for (int j = 0; j < 8; j++) {
      int cc = k0i * 32 + lq * 8 + j;
      int u = cc >> 7, p = (cc & 127) >> 1, par = cc & 1;
      tmp[j] = (short)f2b(Wm[(size_t)(u * 128 + par * 64 + p) * DH + dcol]);
    }
    bw[k0i] = tmp;
  }

  f32x4 acc[3][4] = {};
  ushort kreg[4], vreg[4], breg[4];

  auto LOADCH = [&](int ch) {
    const int s0 = seg * 512 + ch * 32;
    #pragma unroll
    for (int r = 0; r < 4; r++)
      kreg[r] = Kb[(rowbase + s0 + w * 4 + r) * DH + l];
    #pragma unroll
    for (int rr = 0; rr < 4; rr++) {
      size_t ga = (rowbase + s0 + mi * 16 + lq * 4 + rr) * DH + dcol;
      vreg[rr] = Vb[ga];
      breg[rr] = Bgb[ga];
    }
  };

  LOADCH(0);
  __syncthreads();   // zL ready

  for (int ch = 0; ch < 16; ch++) {
    float xpv[4], xnv[4];
    u32 pks[4];
    #pragma unroll
    for (int r = 0; r < 4; r++) {
      float kv = b2f(kreg[r]);
      xpv[r] = fmaxf(kv, 0.f);
      xnv[r] = fmaxf(-kv, 0.f);
      pks[r] = (u32)f2b(xpv[r]) | ((u32)f2b(xnv[r]) << 16);
    }
    ushort4 mp[6];
    #pragma unroll
    for (int u = 0; u < 3; u++) {
      int ie = (l - u - 1) & 127;
      int sl = ie & 63;
      bool sw = ie >= 64;
      #pragma unroll
      for (int r = 0; r < 4; r++) {
        u32 pp = (u32)__shfl((int)pks[r], sl);
        float ps = b2f((ushort)(pp & 0xffff));
        float ns = b2f((ushort)(pp >> 16));
        float xbe = sw ? ns : ps;
        float xbo = sw ? ps : ns;
        ushort bve = f2b(xpv[r] * xbe);
        ushort bvo = f2b(xnv[r] * xbo);
        int row = w * 4 + r;
        mkLd[row][(u * 64 + l) ^ ((row & 7) << 2)] = (u32)bve | ((u32)bvo << 16);
        ((ushort*)&mp[2 * u])[r] = bve;
        ((ushort*)&mp[2 * u + 1])[r] = bvo;
      }
    }
    #pragma unroll
    for (int tt = 0; tt < 6; tt++)
      *(ushort4*)&mkT[l + 64 * tt][w * 4] = mp[tt];
    __syncthreads();   // A: mkLd/mkT ready

    const u32* mkrow = &mkLd[mi * 16 + l15][0];
    const int xr = (l15 & 7) << 2;
    f32x4 an0 = {}, an1 = {}, gacc = {}, zacc = {};
    __builtin_amdgcn_s_setprio(1);
    #pragma unroll
    for (int k0i = 0; k0i < 12; k0i += 2) {
      bf16x8 afA = *(const bf16x8*)(mkrow + ((k0i * 16 + lq * 4) ^ xr));
      bf16x8 afB = *(const bf16x8*)(mkrow + (((k0i + 1) * 16 + lq * 4) ^ xr));
      bf16x8 zfA = *(const bf16x8*)&zL[k0i * 32 + lq * 8];
      bf16x8 zfB = *(const bf16x8*)&zL[(k0i + 1) * 32 + lq * 8];
      an0 = __builtin_amdgcn_mfma_f32_16x16x32_bf16(afA, bw[k0i], an0, 0, 0, 0);
      an1 = __builtin_amdgcn_mfma_f32_16x16x32_bf16(afB, bw[k0i + 1], an1, 0, 0, 0);
      gacc = __builtin_amdgcn_mfma_f32_16x16x32_bf16(afA, afA, gacc, 0, 0, 0);
      gacc = __builtin_amdgcn_mfma_f32_16x16x32_bf16(afB, afB, gacc, 0, 0, 0);
      zacc = __builtin_amdgcn_mfma_f32_16x16x32_bf16(afA, zfA, zacc, 0, 0, 0);
      zacc = __builtin_amdgcn_mfma_f32_16x16x32_bf16(afB, zfB, zacc, 0, 0, 0);
    }
    __builtin_amdgcn_s_setprio(0);
    f32x4 an = an0 + an1;
    float ssqv[4];
    #pragma unroll
    for (int rr = 0; rr < 4; rr++)
      ssqv[rr] = __shfl(gacc[rr], (lq << 4) + lq * 4 + rr);
    {
      ushort4 gp;
      #pragma unroll
      for (int rr = 0; rr < 4; rr++) {
        float inv = 1.0f / fmaxf(sqrtf(ssqv[rr]), 1e-12f);
        float rden = 1.0f / (inv * zacc[rr] + 1e-5f);
        float prev = an[rr] * inv * rden;
        float g = (b2f(vreg[rr]) - prev) * b2f(breg[rr]);
        ((ushort*)&gp)[rr] = f2b(g * inv);
      }
      *(ushort4*)&gLT[dcol][mi * 16 + lq * 4] = gp;
    }
    __syncthreads();   // B: gLT ready

    if (ch < 15) LOADCH(ch + 1);   // prefetch next chunk under assoc

    {
      bf16x8 bfr[4];
      #pragma unroll
      for (int n2 = 0; n2 < 4; n2++) {
        bf16x4 blo = *(const bf16x4*)&gLT[n2 * 16 + l15][lq * 8];
        bf16x4 bhi = *(const bf16x4*)&gLT[n2 * 16 + l15][lq * 8 + 4];
        bfr[n2] = __builtin_shufflevector(blo, bhi, 0, 1, 2, 3, 4, 5, 6, 7);
      }
      __builtin_amdgcn_s_setprio(1);
      #pragma unroll
      for (int m2 = 0; m2 < 3; m2++) {
        bf16x4 alo = *(const bf16x4*)&mkT[w * 48 + m2 * 16 + l15][lq * 8];
        bf16x4 ahi = *(const bf16x4*)&mkT[w * 48 + m2 * 16 + l15][lq * 8 + 4];
        bf16x8 af = __builtin_shufflevector(alo, ahi, 0, 1, 2, 3, 4, 5, 6, 7);
        #pragma unroll
        for (int n2 = 0; n2 < 4; n2++)
          acc[m2][n2] = __builtin_amdgcn_mfma_f32_16x16x32_bf16(af, bfr[n2], acc[m2][n2], 0, 0, 0);
      }
      __builtin_amdgcn_s_setprio(0);
    }
    __syncthreads();   // C: assoc reads done before next phase-1 writes
  }

  ushort* pb = part + ((size_t)bh * 4 + seg) * (DK * DH);
  #pragma unroll
  for (int m2 = 0; m2 < 3; m2++)
    #pragma unroll
    for (int n2 = 0; n2 < 4; n2++)
      #pragma unroll
      for (int rc = 0; rc < 4; rc++)
        pb[(size_t)(w * 48 + m2 * 16 + lq * 4 + rc) * DH + n2 * 16 + l15] =
            f2b(acc[m2][n2][rc]);
}

// ---------------- K3: out = Wmem + sum of 4 bf16 partials ----------------------
__global__ __launch_bounds__(256) void k_reduce(
    const float* __restrict__ Wmem, const ushort* __restrict__ part,
    float* __restrict__ out) {
  size_t i4 = (size_t)blockIdx.x * 256 + threadIdx.x;
  int bh = (int)(i4 / 6144);
  size_t r4 = i4 - (size_t)bh * 6144;
  float4 acc = *(const float4*)(Wmem + i4 * 4);
  #pragma unroll
  for (int k = 0; k < 4; k++) {
    const ushort* pp = part + ((size_t)bh * 4 + k) * (DK * DH) + r4 * 4;
    ushort4 pv = *(const ushort4*)pp;
    acc.x += b2f(pv.x);
    acc.y += b2f(pv.y);
    acc.z += b2f(pv.z);
    acc.w += b2f(pv.w);
  }
  *(float4*)(out + i4 * 4) = acc;
}

extern "C" void kernel_launch(void* const* d_in, const int* in_sizes, int n_in,
                              void* d_out, int out_size, void* d_ws, size_t ws_size,
                              hipStream_t stream) {
  const float* X  = (const float*)d_in[0];
  const float* Wk = (const float*)d_in[1];
  const float* Wv = (const float*)d_in[2];
  const float* Wb = (const float*)d_in[3];
  const float* Wm = (const float*)d_in[4];
  const float* z  = (const float*)d_in[5];
  float* out = (float*)d_out;
  char* ws = (char*)d_ws;

  // ws layout (~140.5 MB; ws_size >= 170 MB proven):
  //   Xb    : 0          .. 33,554,432   (dead after k_proj; part aliases)
  //   Wball : 33,554,432 .. 39,845,888
  //   kvb   : 39,845,888 .. 140,509,184  (K | V | sig(B))
  ushort* Xb    = (ushort*)(ws);
  ushort* Wball = (ushort*)(ws + 33554432ull);
  ushort* kvb   = (ushort*)(ws + 39845888ull);
  ushort* part  = (ushort*)(ws);                  // 25.2 MB, aliases dead Xb
  ushort* Kb  = kvb;
  ushort* Vb  = kvb + (size_t)B_ * H_ * S_ * DH;
  ushort* Bgb = kvb + 2ull * (size_t)B_ * H_ * S_ * DH;

  k_cvt   <<<dim3(2048), 256, 0, stream>>>(X, Wk, Wv, Wb, Xb, Wball);
  k_proj  <<<dim3(64, 8, 3), 512, 0, stream>>>(Xb, Wball, kvb);
  k_fused6<<<dim3(4, B_ * H_), 512, 0, stream>>>(Kb, Vb, Bgb, Wm, z, part);
  k_reduce<<<dim3(3072), 256, 0, stream>>>(Wm, part, out);
}